// Round 8
// baseline (1177.889 us; speedup 1.0000x reference)
//
#include <hip/hip_runtime.h>
#include <math.h>

#define T_STEPS 128
#define B_SZ 128
#define D_SZ 1024
#define H_SZ 1024
#define G4 4096
#define KW 2048  // rows of W = D+H

typedef __attribute__((ext_vector_type(8))) short bf16x8;
typedef __attribute__((ext_vector_type(4))) float f32x4;
typedef unsigned short ushort_t;
typedef unsigned int uint_t;
typedef unsigned long long ull_t;

__device__ __forceinline__ float sigf(float x) { return 1.0f / (1.0f + __expf(-x)); }
__device__ __forceinline__ float tanhfast(float x) { return 1.0f - 2.0f * sigf(-2.0f * x); }

__device__ __forceinline__ ushort_t f2bf(float f) {
  uint_t u = __float_as_uint(f);
  return (ushort_t)((u + 0x7fffu + ((u >> 16) & 1u)) >> 16);
}
__device__ __forceinline__ float bf2f(ushort_t s) {
  return __uint_as_float(((uint_t)s) << 16);
}

#define GLOAD_LDS16(gp, lp)                                                  \
  __builtin_amdgcn_global_load_lds(                                          \
      (const __attribute__((address_space(1))) unsigned int*)(const void*)(gp), \
      (__attribute__((address_space(3))) unsigned int*)(void*)(lp), 16, 0, 0)

// ---------------------------------------------------------------------------
// x fp32 [16384][1024] -> bf16 same layout. 8 elems/thread.
// ---------------------------------------------------------------------------
__global__ __launch_bounds__(256) void convert_x(const float* __restrict__ x,
                                                 ushort_t* __restrict__ xbf) {
  const size_t i8 = ((size_t)blockIdx.x * 256 + threadIdx.x) * 8;
  if (i8 + 8 > (size_t)T_STEPS * B_SZ * D_SZ) return;
  float4 a = *(const float4*)&x[i8];
  float4 b = *(const float4*)&x[i8 + 4];
  ushort_t o[8] = {f2bf(a.x), f2bf(a.y), f2bf(a.z), f2bf(a.w),
                   f2bf(b.x), f2bf(b.y), f2bf(b.z), f2bf(b.w)};
  *(uint4*)&xbf[i8] = *(uint4*)o;
}

// ---------------------------------------------------------------------------
// W fp32 [2048][4096] -> WT bf16 [4096][2048]  (WT[n][k] = W[k][n])
// ---------------------------------------------------------------------------
__global__ __launch_bounds__(256) void transpose_w(const float* __restrict__ W,
                                                   ushort_t* __restrict__ WT) {
  __shared__ float t[32][33];
  const int tx = threadIdx.x & 31;
  const int ty = threadIdx.x >> 5;  // 0..7
  const int k0 = blockIdx.x * 32;
  const int n0 = blockIdx.y * 32;
#pragma unroll
  for (int i = 0; i < 4; ++i)
    t[ty + i * 8][tx] = W[(size_t)(k0 + ty + i * 8) * G4 + n0 + tx];
  __syncthreads();
#pragma unroll
  for (int i = 0; i < 4; ++i)
    WT[(size_t)(n0 + ty + i * 8) * KW + k0 + tx] = f2bf(t[tx][ty + i * 8]);
}

// ---------------------------------------------------------------------------
// hbf0 = bf16(h0 * (1-reset[0]))
// ---------------------------------------------------------------------------
__global__ __launch_bounds__(256) void init_state(const float* __restrict__ h0,
                                                  const float* __restrict__ reset0,
                                                  ushort_t* __restrict__ hbf0) {
  const int i = blockIdx.x * 256 + threadIdx.x;
  if (i >= B_SZ * H_SZ) return;
  hbf0[i] = f2bf(h0[i] * (1.0f - reset0[i >> 10]));
}

// ---------------------------------------------------------------------------
// Gate pre-activation from x:  val = bias[n] + sum_k xbf[m][k]*WT[n][k].
// Output layout for persist blocks: element idx =
//   ((((t*4 + btp)*64 + jt)*512) + r32*16 + c)*4 + g
// where m = t*128 + btp*32 + r32, n = g*1024 + jt*16 + c.
// ---------------------------------------------------------------------------
__global__ __launch_bounds__(256) void xw_mfma2(const ushort_t* __restrict__ xbf,
                                                const ushort_t* __restrict__ WT,
                                                const float* __restrict__ bias,
                                                ushort_t* __restrict__ xwg) {
  __shared__ ushort_t Asb[2][128 * 64];  // [buf][row*64+k], 16KB each
  __shared__ ushort_t Bsb[2][128 * 64];

  const int bid = blockIdx.x;                 // 4096 blocks, 4096%8==0
  const int swz = (bid & 7) * 512 + (bid >> 3);
  const int nt = swz >> 7;                    // 0..31
  const int mt = swz & 127;                   // 0..127
  const int m0 = mt * 128, n0 = nt * 128;
  const int tid = threadIdx.x, lane = tid & 63, wid = tid >> 6;
  const int wr = wid >> 1, wc = wid & 1;
  const int lr = lane & 15, ko = lane >> 4;
  const int srow = lane >> 3;                 // 0..7 row within chunk
  const int skb = (lane & 7) * 16;            // byte within row-window

  f32x4 acc[4][4] = {};

#define XW_STAGE(buf, kt)                                                      \
  {                                                                            \
    const int k0b = (kt) * 128;                                                \
    _Pragma("unroll") for (int i = 0; i < 4; ++i) {                            \
      const int c = wid * 4 + i;                                               \
      const int row = c * 8 + srow;                                            \
      const int sw = skb ^ ((row & 7) << 4);                                   \
      GLOAD_LDS16((const char*)xbf + (size_t)(m0 + row) * 2048 + k0b + sw,     \
                  (char*)&Asb[buf][0] + c * 1024);                             \
      GLOAD_LDS16((const char*)WT + (size_t)(n0 + row) * 4096 + k0b + sw,      \
                  (char*)&Bsb[buf][0] + c * 1024);                             \
    }                                                                          \
  }

  XW_STAGE(0, 0);
  __syncthreads();
  const int xsw = (lr & 7) << 4;
  for (int kt = 0; kt < 16; ++kt) {
    if (kt + 1 < 16) XW_STAGE((kt + 1) & 1, kt + 1);
    const char* Ab = (const char*)&Asb[kt & 1][0] + (wr * 64 + lr) * 128;
    const char* Bb = (const char*)&Bsb[kt & 1][0] + (wc * 64 + lr) * 128;
#pragma unroll
    for (int ks = 0; ks < 2; ++ks) {
      const int kb = (ks * 64 + ko * 16) ^ xsw;
      bf16x8 a[4], b[4];
#pragma unroll
      for (int mi = 0; mi < 4; ++mi) a[mi] = *(const bf16x8*)(Ab + mi * 2048 + kb);
#pragma unroll
      for (int ni = 0; ni < 4; ++ni) b[ni] = *(const bf16x8*)(Bb + ni * 2048 + kb);
#pragma unroll
      for (int mi = 0; mi < 4; ++mi)
#pragma unroll
        for (int ni = 0; ni < 4; ++ni)
          acc[mi][ni] = __builtin_amdgcn_mfma_f32_16x16x32_bf16(a[mi], b[ni], acc[mi][ni], 0, 0, 0);
    }
    __syncthreads();
  }

  const int rr = ko * 4;
#pragma unroll
  for (int ni = 0; ni < 4; ++ni) {
    const int n = n0 + wc * 64 + ni * 16 + lr;
    const int gg = n >> 10;
    const int jj = n & 1023;
    const float bn = bias[n];
#pragma unroll
    for (int mi = 0; mi < 4; ++mi) {
#pragma unroll
      for (int r = 0; r < 4; ++r) {
        const int m = m0 + wr * 64 + mi * 16 + rr + r;
        const int tt = m >> 7;
        const int btp = (m & 127) >> 5;
        const int r32 = m & 31;
        xwg[((((size_t)tt * 4 + btp) * 64 + (jj >> 4)) * 512 + r32 * 16 + (jj & 15)) * 4 + gg] =
            f2bf(acc[mi][ni][r] + bn);
      }
    }
  }
}

// ---------------------------------------------------------------------------
// Persistent LSTM recurrence. 256 blocks (1/CU) x 512 thr.
// Block (jt = bid&63, btp = bid>>6) touches ONLY h rows [btp*32,+32) -> the
// grid decomposes into 4 INDEPENDENT groups of 64 blocks; sync is per-group.
// Barrier: each block stores generation t+1 to its own arrival word (no
// contended atomics, monotonic -> no ABA); wave 0 of every block polls all 64
// group words with one 64-lane load + __all. Groups may drift in t (buffers
// are row-disjoint). Next step's xwg/reset prefetched during the poll window.
// Wh resident forever: k-half in LDS (swizzled) + k-half in 16 VGPR frags.
// ---------------------------------------------------------------------------
__global__ __launch_bounds__(512) void lstm_persist3(
    const ushort_t* __restrict__ hbf0,  // [128][1024] premasked bf16
    const float* __restrict__ c0,       // [128][1024] raw
    const float* __restrict__ reset,    // [T][128]
    const ushort_t* __restrict__ xwg,   // relayout, bias included
    const ushort_t* __restrict__ WT,    // [4096][2048]
    float* __restrict__ out,            // [T*128][1024] then hT, cT
    ushort_t* __restrict__ hbuf,        // [2][128][1024] premasked bf16
    uint_t* __restrict__ bar)           // [4][256] arrival words, zeroed
{
  __shared__ ushort_t WhL[64 * 512];   // [nr][k half], swizzled, 64 KB
  __shared__ ushort_t Ah[32 * 1024];   // [row][k], swizzled, 64 KB
  __shared__ float sc[2][4][16][17];   // [mh][g][brow][jcol], 8.7 KB

  const int tid = threadIdx.x;
  const int bid = blockIdx.x;   // 0..255
  const int jt = bid & 63;
  const int btp = bid >> 6;     // 0..3 = batch-group
  const int b0 = btp * 32;
  const int lane = tid & 63;
  const int wid = tid >> 6;     // 0..7
  const int g = wid & 3;
  const int mh = wid >> 2;
  const int lr = lane & 15;
  const int ko = lane >> 4;

  // ---- stage Wh k in [1024,1536) into LDS (once) ----
  for (int p = 0; p < 8; ++p) {
    const int id = p * 512 + tid;       // 0..4095
    const int wrw = id >> 6;            // 0..63 local n-row
    const int kb = (id & 63) * 16;      // byte in [0,1024)
    const int n = (wrw >> 4) * H_SZ + jt * 16 + (wrw & 15);
    const uint4 v = *(const uint4*)((const char*)WT + (size_t)n * 4096 + 2048 + kb);
    *(uint4*)((char*)WhL + wrw * 1024 + (kb ^ ((wrw & 7) << 4))) = v;
  }

  // ---- permanent B regs: Wh k in [1536,2048) ----
  const char* wrow = (const char*)WT + (size_t)(g * H_SZ + jt * 16 + lr) * 4096;
  bf16x8 breg[16];
#pragma unroll
  for (int q = 0; q < 16; ++q)
    breg[q] = *(const bf16x8*)(wrow + 3072 + q * 64 + ko * 16);

  // ---- per-thread output element state ----
  const int row = tid >> 4;     // 0..31
  const int col = tid & 15;
  const int b = b0 + row;
  const int j = jt * 16 + col;
  const size_t so = (size_t)b * H_SZ + j;
  float creg = c0[so] * (1.0f - reset[b]);

  const int swzl = (lr & 7) << 4;
  const char* aBase = (const char*)Ah + (mh * 16 + lr) * 2048;
  const char* bBase = (const char*)WhL + (g * 16 + lr) * 1024;

  // prefetched per-step operands (step 0)
  ull_t xwv = *(const ull_t*)(xwg + (((size_t)0 * 4 + btp) * 64 + jt) * 512 * 4 + (size_t)tid * 4);
  float mn = 1.0f - reset[B_SZ + b];  // mask for t=1 (T_STEPS > 1)

  for (int t = 0; t < T_STEPS; ++t) {
    // ---- A-stage: 32 h-rows via L3-coherent 8B loads -> LDS (swizzled) ----
    const ull_t* hsrc = (t == 0)
        ? (const ull_t*)hbf0
        : (const ull_t*)(hbuf + (size_t)(t & 1) * (B_SZ * H_SZ));
    ull_t av[16];
#pragma unroll
    for (int p = 0; p < 16; ++p) {
      const int id = p * 512 + tid;     // 0..8191
      const int ar = id >> 8;           // 0..31
      const int ac = id & 255;          // 8B chunk in row
      av[p] = __hip_atomic_load(hsrc + (size_t)(b0 + ar) * 256 + ac,
                                __ATOMIC_RELAXED, __HIP_MEMORY_SCOPE_AGENT);
    }
#pragma unroll
    for (int p = 0; p < 16; ++p) {
      const int id = p * 512 + tid;
      const int ar = id >> 8;
      const int ac = id & 255;
      *(ull_t*)((char*)Ah + ar * 2048 + ((ac * 8) ^ ((ar & 7) << 4))) = av[p];
    }
    __syncthreads();

    // ---- GEMM: 16x16 out per wave, K=1024 (LDS half + reg half) ----
    f32x4 acc = {};
#pragma unroll
    for (int ks = 0; ks < 16; ++ks) {
      bf16x8 a = *(const bf16x8*)(aBase + ((ks * 64 + ko * 16) ^ swzl));
      bf16x8 bb = *(const bf16x8*)(bBase + ((ks * 64 + ko * 16) ^ swzl));
      acc = __builtin_amdgcn_mfma_f32_16x16x32_bf16(a, bb, acc, 0, 0, 0);
    }
#pragma unroll
    for (int ks = 0; ks < 16; ++ks) {
      bf16x8 a = *(const bf16x8*)(aBase + (((16 + ks) * 64 + ko * 16) ^ swzl));
      acc = __builtin_amdgcn_mfma_f32_16x16x32_bf16(a, breg[ks], acc, 0, 0, 0);
    }
#pragma unroll
    for (int r = 0; r < 4; ++r) sc[mh][g][ko * 4 + r][lr] = acc[r];
    __syncthreads();

    // ---- fused elementwise: 512 threads -> 32 rows x 16 cols ----
    const float gi = sc[row >> 4][0][row & 15][col] + bf2f((ushort_t)xwv);
    const float gg = sc[row >> 4][1][row & 15][col] + bf2f((ushort_t)(xwv >> 16));
    const float gf = sc[row >> 4][2][row & 15][col] + bf2f((ushort_t)(xwv >> 32));
    const float go = sc[row >> 4][3][row & 15][col] + bf2f((ushort_t)(xwv >> 48));
    const float f = sigf(gf + 1.0f);
    const float cn = f * creg + sigf(gi) * tanhfast(gg);
    const float hn = sigf(go) * tanhfast(cn);
    out[(size_t)t * (B_SZ * H_SZ) + so] = hn;
    creg = cn * mn;

    if (t < T_STEPS - 1) {
      // premasked h_{t+1} via L3 write-through store
      __hip_atomic_store(hbuf + (size_t)((t + 1) & 1) * (B_SZ * H_SZ) + so,
                         f2bf(hn * mn), __ATOMIC_RELAXED, __HIP_MEMORY_SCOPE_AGENT);
      asm volatile("s_waitcnt vmcnt(0)" ::: "memory");  // drain h to L3 (per wave)
      __syncthreads();                                  // whole block drained

      // prefetch next step's operands (independent of the barrier)
      xwv = *(const ull_t*)(xwg + ((((size_t)(t + 1) * 4 + btp) * 64 + jt) * 512 + tid) * 4);
      mn = (t + 1 < T_STEPS - 1) ? (1.0f - reset[(size_t)(t + 2) * B_SZ + b]) : 1.0f;

      // ---- per-group barrier: own-word arrival + 64-lane poll ----
      if (wid == 0) {
        if (tid == 0)
          __hip_atomic_store(&bar[btp * 256 + jt], (uint_t)(t + 1),
                             __ATOMIC_RELAXED, __HIP_MEMORY_SCOPE_AGENT);
        const uint_t* aw = bar + btp * 256 + lane;
        uint_t it = 0;
        for (;;) {
          const uint_t v = __hip_atomic_load(aw, __ATOMIC_RELAXED,
                                             __HIP_MEMORY_SCOPE_AGENT);
          if (__all((int)v > t)) break;
          __builtin_amdgcn_s_sleep(1);
          if (++it > 200000u) break;  // bounded: fail visibly, don't hang
        }
      }
      __syncthreads();
    } else {
      float* hT = out + (size_t)T_STEPS * (B_SZ * H_SZ);
      float* cT = hT + (B_SZ * H_SZ);
      hT[so] = hn;
      cT[so] = cn;  // unmasked at last step
    }
  }
}

extern "C" void kernel_launch(void* const* d_in, const int* in_sizes, int n_in,
                              void* d_out, int out_size, void* d_ws, size_t ws_size,
                              hipStream_t stream) {
  (void)in_sizes; (void)n_in; (void)out_size; (void)ws_size;
  const float* x = (const float*)d_in[0];
  const float* h0 = (const float*)d_in[1];
  const float* c0 = (const float*)d_in[2];
  const float* reset = (const float*)d_in[3];
  const float* W = (const float*)d_in[4];
  const float* bias = (const float*)d_in[5];
  float* out = (float*)d_out;

  const size_t TB = (size_t)T_STEPS * B_SZ;  // 16384
  const size_t SE = (size_t)B_SZ * H_SZ;     // 131072

  // ws layout (4KB-aligned chunks)
  char* p = (char*)d_ws;
  uint_t* bar = (uint_t*)p;               p += 4096;
  ushort_t* WT = (ushort_t*)p;            p += (size_t)G4 * KW * 2;
  ushort_t* xbf = (ushort_t*)p;           p += TB * D_SZ * 2;
  ushort_t* xwg = (ushort_t*)p;           p += TB * G4 * 2;
  ushort_t* hbf0 = (ushort_t*)p;          p += SE * 2;
  ushort_t* hbuf = (ushort_t*)p;          p += 2 * SE * 2;

  hipMemsetAsync(bar, 0, 4096, stream);
  convert_x<<<dim3((int)(TB * D_SZ / 8 / 256)), 256, 0, stream>>>(x, xbf);
  transpose_w<<<dim3(KW / 32, G4 / 32), 256, 0, stream>>>(W, WT);
  init_state<<<dim3((int)((SE + 255) / 256)), 256, 0, stream>>>(h0, reset, hbf0);
  xw_mfma2<<<dim3(4096), 256, 0, stream>>>(xbf, WT, bias, xwg);

  lstm_persist3<<<dim3(256), 512, 0, stream>>>(hbf0, c0, reset, xwg, WT, out, hbuf, bar);
}

// Round 9
// 976.092 us; speedup vs baseline: 1.2067x; 1.2067x over previous
//
#include <hip/hip_runtime.h>
#include <math.h>

#define T_STEPS 128
#define B_SZ 128
#define D_SZ 1024
#define H_SZ 1024
#define G4 4096
#define KW 2048  // rows of W = D+H

typedef __attribute__((ext_vector_type(8))) short bf16x8;
typedef __attribute__((ext_vector_type(4))) float f32x4;
typedef unsigned short ushort_t;
typedef unsigned int uint_t;
typedef unsigned long long ull_t;

__device__ __forceinline__ float sigf(float x) { return 1.0f / (1.0f + __expf(-x)); }
__device__ __forceinline__ float tanhfast(float x) { return 1.0f - 2.0f * sigf(-2.0f * x); }

__device__ __forceinline__ ushort_t f2bf(float f) {
  uint_t u = __float_as_uint(f);
  return (ushort_t)((u + 0x7fffu + ((u >> 16) & 1u)) >> 16);
}
__device__ __forceinline__ float bf2f(ushort_t s) {
  return __uint_as_float(((uint_t)s) << 16);
}

#define GLOAD_LDS16(gp, lp)                                                  \
  __builtin_amdgcn_global_load_lds(                                          \
      (const __attribute__((address_space(1))) unsigned int*)(const void*)(gp), \
      (__attribute__((address_space(3))) unsigned int*)(void*)(lp), 16, 0, 0)

// ---------------------------------------------------------------------------
// x fp32 [16384][1024] -> bf16 same layout. 8 elems/thread.
// ---------------------------------------------------------------------------
__global__ __launch_bounds__(256) void convert_x(const float* __restrict__ x,
                                                 ushort_t* __restrict__ xbf) {
  const size_t i8 = ((size_t)blockIdx.x * 256 + threadIdx.x) * 8;
  if (i8 + 8 > (size_t)T_STEPS * B_SZ * D_SZ) return;
  float4 a = *(const float4*)&x[i8];
  float4 b = *(const float4*)&x[i8 + 4];
  ushort_t o[8] = {f2bf(a.x), f2bf(a.y), f2bf(a.z), f2bf(a.w),
                   f2bf(b.x), f2bf(b.y), f2bf(b.z), f2bf(b.w)};
  *(uint4*)&xbf[i8] = *(uint4*)o;
}

// ---------------------------------------------------------------------------
// W fp32 [2048][4096] -> WT bf16 [4096][2048]  (WT[n][k] = W[k][n])
// ---------------------------------------------------------------------------
__global__ __launch_bounds__(256) void transpose_w(const float* __restrict__ W,
                                                   ushort_t* __restrict__ WT) {
  __shared__ float t[32][33];
  const int tx = threadIdx.x & 31;
  const int ty = threadIdx.x >> 5;  // 0..7
  const int k0 = blockIdx.x * 32;
  const int n0 = blockIdx.y * 32;
#pragma unroll
  for (int i = 0; i < 4; ++i)
    t[ty + i * 8][tx] = W[(size_t)(k0 + ty + i * 8) * G4 + n0 + tx];
  __syncthreads();
#pragma unroll
  for (int i = 0; i < 4; ++i)
    WT[(size_t)(n0 + ty + i * 8) * KW + k0 + tx] = f2bf(t[tx][ty + i * 8]);
}

// ---------------------------------------------------------------------------
// hbf0 = bf16(h0 * (1-reset[0]))
// ---------------------------------------------------------------------------
__global__ __launch_bounds__(256) void init_state(const float* __restrict__ h0,
                                                  const float* __restrict__ reset0,
                                                  ushort_t* __restrict__ hbf0) {
  const int i = blockIdx.x * 256 + threadIdx.x;
  if (i >= B_SZ * H_SZ) return;
  hbf0[i] = f2bf(h0[i] * (1.0f - reset0[i >> 10]));
}

// ---------------------------------------------------------------------------
// Gate pre-activation from x:  val = bias[n] + sum_k xbf[m][k]*WT[n][k].
// Output layout for persist blocks: element idx =
//   ((((t*4 + btp)*64 + jt)*512) + r32*16 + c)*4 + g
// where m = t*128 + btp*32 + r32, n = g*1024 + jt*16 + c.
// ---------------------------------------------------------------------------
__global__ __launch_bounds__(256) void xw_mfma2(const ushort_t* __restrict__ xbf,
                                                const ushort_t* __restrict__ WT,
                                                const float* __restrict__ bias,
                                                ushort_t* __restrict__ xwg) {
  __shared__ ushort_t Asb[2][128 * 64];  // [buf][row*64+k], 16KB each
  __shared__ ushort_t Bsb[2][128 * 64];

  const int bid = blockIdx.x;                 // 4096 blocks, 4096%8==0
  const int swz = (bid & 7) * 512 + (bid >> 3);
  const int nt = swz >> 7;                    // 0..31
  const int mt = swz & 127;                   // 0..127
  const int m0 = mt * 128, n0 = nt * 128;
  const int tid = threadIdx.x, lane = tid & 63, wid = tid >> 6;
  const int wr = wid >> 1, wc = wid & 1;
  const int lr = lane & 15, ko = lane >> 4;
  const int srow = lane >> 3;                 // 0..7 row within chunk
  const int skb = (lane & 7) * 16;            // byte within row-window

  f32x4 acc[4][4] = {};

#define XW_STAGE(buf, kt)                                                      \
  {                                                                            \
    const int k0b = (kt) * 128;                                                \
    _Pragma("unroll") for (int i = 0; i < 4; ++i) {                            \
      const int c = wid * 4 + i;                                               \
      const int row = c * 8 + srow;                                            \
      const int sw = skb ^ ((row & 7) << 4);                                   \
      GLOAD_LDS16((const char*)xbf + (size_t)(m0 + row) * 2048 + k0b + sw,     \
                  (char*)&Asb[buf][0] + c * 1024);                             \
      GLOAD_LDS16((const char*)WT + (size_t)(n0 + row) * 4096 + k0b + sw,      \
                  (char*)&Bsb[buf][0] + c * 1024);                             \
    }                                                                          \
  }

  XW_STAGE(0, 0);
  __syncthreads();
  const int xsw = (lr & 7) << 4;
  for (int kt = 0; kt < 16; ++kt) {
    if (kt + 1 < 16) XW_STAGE((kt + 1) & 1, kt + 1);
    const char* Ab = (const char*)&Asb[kt & 1][0] + (wr * 64 + lr) * 128;
    const char* Bb = (const char*)&Bsb[kt & 1][0] + (wc * 64 + lr) * 128;
#pragma unroll
    for (int ks = 0; ks < 2; ++ks) {
      const int kb = (ks * 64 + ko * 16) ^ xsw;
      bf16x8 a[4], b[4];
#pragma unroll
      for (int mi = 0; mi < 4; ++mi) a[mi] = *(const bf16x8*)(Ab + mi * 2048 + kb);
#pragma unroll
      for (int ni = 0; ni < 4; ++ni) b[ni] = *(const bf16x8*)(Bb + ni * 2048 + kb);
#pragma unroll
      for (int mi = 0; mi < 4; ++mi)
#pragma unroll
        for (int ni = 0; ni < 4; ++ni)
          acc[mi][ni] = __builtin_amdgcn_mfma_f32_16x16x32_bf16(a[mi], b[ni], acc[mi][ni], 0, 0, 0);
    }
    __syncthreads();
  }

  const int rr = ko * 4;
#pragma unroll
  for (int ni = 0; ni < 4; ++ni) {
    const int n = n0 + wc * 64 + ni * 16 + lr;
    const int gg = n >> 10;
    const int jj = n & 1023;
    const float bn = bias[n];
#pragma unroll
    for (int mi = 0; mi < 4; ++mi) {
#pragma unroll
      for (int r = 0; r < 4; ++r) {
        const int m = m0 + wr * 64 + mi * 16 + rr + r;
        const int tt = m >> 7;
        const int btp = (m & 127) >> 5;
        const int r32 = m & 31;
        xwg[((((size_t)tt * 4 + btp) * 64 + (jj >> 4)) * 512 + r32 * 16 + (jj & 15)) * 4 + gg] =
            f2bf(acc[mi][ni][r] + bn);
      }
    }
  }
}

// ---------------------------------------------------------------------------
// Persistent LSTM recurrence. 256 blocks (1/CU) x 512 thr.
// Block (jt=bid&63, btp=bid>>6) touches ONLY h rows [btp*32,+32): 4
// independent groups of 64 blocks, per-group sync.
// h transport: per-step RING buffer (each address written once via sc
// write-through store, read once) -> readers use NORMAL CACHED loads
// (global_load_lds w=16): pipelined, and same-XCD blocks share the tile
// through L2 (L3 traffic 16MB -> ~2MB/step).
// Barrier: own-word sc arrival store; group aggregator (jt==0) scans 64
// words with one 64-lane load, sets one flag; others poll that single word.
// Wh resident forever: k-half in LDS (swizzled) + k-half in 16 VGPR frags.
// ---------------------------------------------------------------------------
__global__ __launch_bounds__(512) void lstm_persist4(
    const ushort_t* __restrict__ hbf0,  // [128][1024] premasked bf16
    const float* __restrict__ c0,       // [128][1024] raw
    const float* __restrict__ reset,    // [T][128]
    const ushort_t* __restrict__ xwg,   // relayout, bias included
    const ushort_t* __restrict__ WT,    // [4096][2048]
    float* __restrict__ out,            // [T*128][1024] then hT, cT
    ushort_t* __restrict__ hring,       // [T][128][1024] premasked bf16 ring
    uint_t* __restrict__ bar)           // arrivals + flags, zeroed
{
  __shared__ ushort_t WhL[64 * 512];   // [nr][k half], swizzled, 64 KB
  __shared__ ushort_t Ah[32 * 1024];   // [row][k], swizzled, 64 KB
  __shared__ float sc[2][4][16][17];   // [mh][g][brow][jcol], 8.7 KB

  const int tid = threadIdx.x;
  const int bid = blockIdx.x;   // 0..255
  const int jt = bid & 63;
  const int btp = bid >> 6;     // 0..3 = batch-group
  const int b0 = btp * 32;
  const int lane = tid & 63;
  const int wid = tid >> 6;     // 0..7
  const int g = wid & 3;
  const int mh = wid >> 2;
  const int lr = lane & 15;
  const int ko = lane >> 4;
  const size_t SE = (size_t)B_SZ * H_SZ;

  uint_t* const arr = bar + btp * 256;        // 64 arrival words (own 1KB zone)
  uint_t* const flg = bar + btp * 256 + 128;  // flag word, separate 512B line

  // ---- stage Wh k in [1024,1536) into LDS (once) ----
  for (int p = 0; p < 8; ++p) {
    const int id = p * 512 + tid;       // 0..4095
    const int wrw = id >> 6;            // 0..63 local n-row
    const int kb = (id & 63) * 16;      // byte in [0,1024)
    const int n = (wrw >> 4) * H_SZ + jt * 16 + (wrw & 15);
    const uint4 v = *(const uint4*)((const char*)WT + (size_t)n * 4096 + 2048 + kb);
    *(uint4*)((char*)WhL + wrw * 1024 + (kb ^ ((wrw & 7) << 4))) = v;
  }

  // ---- permanent B regs: Wh k in [1536,2048) ----
  const char* wrow = (const char*)WT + (size_t)(g * H_SZ + jt * 16 + lr) * 4096;
  bf16x8 breg[16];
#pragma unroll
  for (int q = 0; q < 16; ++q)
    breg[q] = *(const bf16x8*)(wrow + 3072 + q * 64 + ko * 16);

  // ---- per-thread output element state ----
  const int row = tid >> 4;     // 0..31
  const int col = tid & 15;
  const int b = b0 + row;
  const int j = jt * 16 + col;
  const size_t so = (size_t)b * H_SZ + j;
  float creg = c0[so] * (1.0f - reset[b]);

  const int swzl = (lr & 7) << 4;
  const char* aBase = (const char*)Ah + (mh * 16 + lr) * 2048;
  const char* bBase = (const char*)WhL + (g * 16 + lr) * 1024;

  // prefetched per-step operands (step 0 / mask for t=1)
  ull_t xwv = *(const ull_t*)(xwg + (((size_t)btp * 64 + jt) * 512 + tid) * 4);
  float mn = 1.0f - reset[B_SZ + b];

  for (int t = 0; t < T_STEPS; ++t) {
    // ---- A-stage: 32 h-rows via cached global_load_lds (pre-swizzled src) --
    const char* hsrc = (t == 0) ? (const char*)hbf0
                                : (const char*)(hring + (size_t)t * SE);
#pragma unroll
    for (int i = 0; i < 8; ++i) {
      const int c = wid * 8 + i;        // 0..63 (1KB chunks)
      const int hrow = c >> 1;          // 0..31
      const int half = (c & 1) * 1024;  // byte offset in 2048B row
      const int kb = half + lane * 16;
      const int src = kb ^ ((hrow & 7) << 4);
      GLOAD_LDS16(hsrc + (size_t)(b0 + hrow) * 2048 + src,
                  (char*)Ah + hrow * 2048 + half);
    }
    __syncthreads();

    // ---- GEMM: 16x16 out per wave, K=1024 (LDS half + reg half) ----
    f32x4 acc = {};
#pragma unroll
    for (int ks = 0; ks < 16; ++ks) {
      bf16x8 a = *(const bf16x8*)(aBase + ((ks * 64 + ko * 16) ^ swzl));
      bf16x8 bb = *(const bf16x8*)(bBase + ((ks * 64 + ko * 16) ^ swzl));
      acc = __builtin_amdgcn_mfma_f32_16x16x32_bf16(a, bb, acc, 0, 0, 0);
    }
#pragma unroll
    for (int ks = 0; ks < 16; ++ks) {
      bf16x8 a = *(const bf16x8*)(aBase + (((16 + ks) * 64 + ko * 16) ^ swzl));
      acc = __builtin_amdgcn_mfma_f32_16x16x32_bf16(a, breg[ks], acc, 0, 0, 0);
    }
#pragma unroll
    for (int r = 0; r < 4; ++r) sc[mh][g][ko * 4 + r][lr] = acc[r];
    __syncthreads();

    // ---- fused elementwise: 512 threads -> 32 rows x 16 cols ----
    const float gi = sc[row >> 4][0][row & 15][col] + bf2f((ushort_t)xwv);
    const float gg = sc[row >> 4][1][row & 15][col] + bf2f((ushort_t)(xwv >> 16));
    const float gf = sc[row >> 4][2][row & 15][col] + bf2f((ushort_t)(xwv >> 32));
    const float go = sc[row >> 4][3][row & 15][col] + bf2f((ushort_t)(xwv >> 48));
    const float f = sigf(gf + 1.0f);
    const float cn = f * creg + sigf(gi) * tanhfast(gg);
    const float hn = sigf(go) * tanhfast(cn);
    out[(size_t)t * SE + so] = hn;
    creg = cn * mn;

    if (t < T_STEPS - 1) {
      // h_{t+1} premasked -> hring[t+1] (write-through; fresh address)
      __hip_atomic_store(hring + (size_t)(t + 1) * SE + so, f2bf(hn * mn),
                         __ATOMIC_RELAXED, __HIP_MEMORY_SCOPE_AGENT);
      asm volatile("s_waitcnt vmcnt(0)" ::: "memory");  // drain h to L3
      __syncthreads();                                  // whole block drained

      // prefetch next step's operands (independent of the barrier)
      xwv = *(const ull_t*)(xwg + ((((size_t)(t + 1) * 4 + btp) * 64 + jt) * 512 + tid) * 4);
      mn = (t + 1 < T_STEPS - 1) ? (1.0f - reset[(size_t)(t + 2) * B_SZ + b]) : 1.0f;

      // ---- per-group barrier: own-word arrival; aggregator scans; flag ----
      if (wid == 0) {
        if (lane == 0)
          __hip_atomic_store(&arr[jt], (uint_t)(t + 1),
                             __ATOMIC_RELAXED, __HIP_MEMORY_SCOPE_AGENT);
        if (jt == 0) {
          uint_t it = 0;
          for (;;) {
            const uint_t v = __hip_atomic_load(&arr[lane], __ATOMIC_RELAXED,
                                               __HIP_MEMORY_SCOPE_AGENT);
            if (__all((int)v > t)) break;
            __builtin_amdgcn_s_sleep(1);
            if (++it > 1000000u) break;  // bounded: fail visibly, don't hang
          }
          if (lane == 0)
            __hip_atomic_store(flg, (uint_t)(t + 1),
                               __ATOMIC_RELAXED, __HIP_MEMORY_SCOPE_AGENT);
        } else {
          uint_t it = 0;
          for (;;) {
            const uint_t v = __hip_atomic_load(flg, __ATOMIC_RELAXED,
                                               __HIP_MEMORY_SCOPE_AGENT);
            if ((int)v > t) break;
            __builtin_amdgcn_s_sleep(1);
            if (++it > 1000000u) break;
          }
        }
      }
      __syncthreads();
    } else {
      float* hT = out + (size_t)T_STEPS * SE;
      float* cT = hT + SE;
      hT[so] = hn;
      cT[so] = cn;  // unmasked at last step
    }
  }
}

extern "C" void kernel_launch(void* const* d_in, const int* in_sizes, int n_in,
                              void* d_out, int out_size, void* d_ws, size_t ws_size,
                              hipStream_t stream) {
  (void)in_sizes; (void)n_in; (void)out_size; (void)ws_size;
  const float* x = (const float*)d_in[0];
  const float* h0 = (const float*)d_in[1];
  const float* c0 = (const float*)d_in[2];
  const float* reset = (const float*)d_in[3];
  const float* W = (const float*)d_in[4];
  const float* bias = (const float*)d_in[5];
  float* out = (float*)d_out;

  const size_t TB = (size_t)T_STEPS * B_SZ;  // 16384
  const size_t SE = (size_t)B_SZ * H_SZ;     // 131072

  // ws layout (~218 MB total; proven ws_size >= 269 MB in R1)
  char* p = (char*)d_ws;
  uint_t* bar = (uint_t*)p;               p += 4096;
  ushort_t* WT = (ushort_t*)p;            p += (size_t)G4 * KW * 2;   // 16.8MB
  ushort_t* xbf = (ushort_t*)p;           p += TB * D_SZ * 2;         // 33.6MB
  ushort_t* xwg = (ushort_t*)p;           p += TB * G4 * 2;           // 134.2MB
  ushort_t* hbf0 = (ushort_t*)p;          p += SE * 2;                // 0.26MB
  ushort_t* hring = (ushort_t*)p;         p += (size_t)T_STEPS * SE * 2;  // 33.6MB

  hipMemsetAsync(bar, 0, 4096, stream);
  convert_x<<<dim3((int)(TB * D_SZ / 8 / 256)), 256, 0, stream>>>(x, xbf);
  transpose_w<<<dim3(KW / 32, G4 / 32), 256, 0, stream>>>(W, WT);
  init_state<<<dim3((int)((SE + 255) / 256)), 256, 0, stream>>>(h0, reset, hbf0);
  xw_mfma2<<<dim3(4096), 256, 0, stream>>>(xbf, WT, bias, xwg);

  lstm_persist4<<<dim3(256), 512, 0, stream>>>(hbf0, c0, reset, xwg, WT, out, hring, bar);
}

// Round 10
// 884.111 us; speedup vs baseline: 1.3323x; 1.1040x over previous
//
#include <hip/hip_runtime.h>
#include <math.h>

#define T_STEPS 128
#define B_SZ 128
#define D_SZ 1024
#define H_SZ 1024
#define G4 4096
#define KW 2048  // rows of W = D+H

typedef __attribute__((ext_vector_type(8))) short bf16x8;
typedef __attribute__((ext_vector_type(4))) float f32x4;
typedef unsigned short ushort_t;
typedef unsigned int uint_t;
typedef unsigned long long ull_t;

__device__ __forceinline__ float sigf(float x) { return 1.0f / (1.0f + __expf(-x)); }
__device__ __forceinline__ float tanhfast(float x) { return 1.0f - 2.0f * sigf(-2.0f * x); }

__device__ __forceinline__ ushort_t f2bf(float f) {
  uint_t u = __float_as_uint(f);
  return (ushort_t)((u + 0x7fffu + ((u >> 16) & 1u)) >> 16);
}
__device__ __forceinline__ float bf2f(ushort_t s) {
  return __uint_as_float(((uint_t)s) << 16);
}

#define GLOAD_LDS16(gp, lp)                                                  \
  __builtin_amdgcn_global_load_lds(                                          \
      (const __attribute__((address_space(1))) unsigned int*)(const void*)(gp), \
      (__attribute__((address_space(3))) unsigned int*)(void*)(lp), 16, 0, 0)

// ---------------------------------------------------------------------------
// x fp32 [16384][1024] -> bf16 same layout. 8 elems/thread.
// ---------------------------------------------------------------------------
__global__ __launch_bounds__(256) void convert_x(const float* __restrict__ x,
                                                 ushort_t* __restrict__ xbf) {
  const size_t i8 = ((size_t)blockIdx.x * 256 + threadIdx.x) * 8;
  if (i8 + 8 > (size_t)T_STEPS * B_SZ * D_SZ) return;
  float4 a = *(const float4*)&x[i8];
  float4 b = *(const float4*)&x[i8 + 4];
  ushort_t o[8] = {f2bf(a.x), f2bf(a.y), f2bf(a.z), f2bf(a.w),
                   f2bf(b.x), f2bf(b.y), f2bf(b.z), f2bf(b.w)};
  *(uint4*)&xbf[i8] = *(uint4*)o;
}

// ---------------------------------------------------------------------------
// W fp32 [2048][4096] -> WT bf16 [4096][2048]  (WT[n][k] = W[k][n])
// ---------------------------------------------------------------------------
__global__ __launch_bounds__(256) void transpose_w(const float* __restrict__ W,
                                                   ushort_t* __restrict__ WT) {
  __shared__ float t[32][33];
  const int tx = threadIdx.x & 31;
  const int ty = threadIdx.x >> 5;  // 0..7
  const int k0 = blockIdx.x * 32;
  const int n0 = blockIdx.y * 32;
#pragma unroll
  for (int i = 0; i < 4; ++i)
    t[ty + i * 8][tx] = W[(size_t)(k0 + ty + i * 8) * G4 + n0 + tx];
  __syncthreads();
#pragma unroll
  for (int i = 0; i < 4; ++i)
    WT[(size_t)(n0 + ty + i * 8) * KW + k0 + tx] = f2bf(t[tx][ty + i * 8]);
}

// ---------------------------------------------------------------------------
// hbf0 = bf16(h0 * (1-reset[0]))
// ---------------------------------------------------------------------------
__global__ __launch_bounds__(256) void init_state(const float* __restrict__ h0,
                                                  const float* __restrict__ reset0,
                                                  ushort_t* __restrict__ hbf0) {
  const int i = blockIdx.x * 256 + threadIdx.x;
  if (i >= B_SZ * H_SZ) return;
  hbf0[i] = f2bf(h0[i] * (1.0f - reset0[i >> 10]));
}

// ---------------------------------------------------------------------------
// Gate pre-activation from x:  val = bias[n] + sum_k xbf[m][k]*WT[n][k].
// Output layout for persist blocks: element idx =
//   ((((t*4 + btp)*64 + jt)*512) + r32*16 + c)*4 + g
// where m = t*128 + btp*32 + r32, n = g*1024 + jt*16 + c.
// ---------------------------------------------------------------------------
__global__ __launch_bounds__(256) void xw_mfma2(const ushort_t* __restrict__ xbf,
                                                const ushort_t* __restrict__ WT,
                                                const float* __restrict__ bias,
                                                ushort_t* __restrict__ xwg) {
  __shared__ ushort_t Asb[2][128 * 64];  // [buf][row*64+k], 16KB each
  __shared__ ushort_t Bsb[2][128 * 64];

  const int bid = blockIdx.x;                 // 4096 blocks, 4096%8==0
  const int swz = (bid & 7) * 512 + (bid >> 3);
  const int nt = swz >> 7;                    // 0..31
  const int mt = swz & 127;                   // 0..127
  const int m0 = mt * 128, n0 = nt * 128;
  const int tid = threadIdx.x, lane = tid & 63, wid = tid >> 6;
  const int wr = wid >> 1, wc = wid & 1;
  const int lr = lane & 15, ko = lane >> 4;
  const int srow = lane >> 3;                 // 0..7 row within chunk
  const int skb = (lane & 7) * 16;            // byte within row-window

  f32x4 acc[4][4] = {};

#define XW_STAGE(buf, kt)                                                      \
  {                                                                            \
    const int k0b = (kt) * 128;                                                \
    _Pragma("unroll") for (int i = 0; i < 4; ++i) {                            \
      const int c = wid * 4 + i;                                               \
      const int row = c * 8 + srow;                                            \
      const int sw = skb ^ ((row & 7) << 4);                                   \
      GLOAD_LDS16((const char*)xbf + (size_t)(m0 + row) * 2048 + k0b + sw,     \
                  (char*)&Asb[buf][0] + c * 1024);                             \
      GLOAD_LDS16((const char*)WT + (size_t)(n0 + row) * 4096 + k0b + sw,      \
                  (char*)&Bsb[buf][0] + c * 1024);                             \
    }                                                                          \
  }

  XW_STAGE(0, 0);
  __syncthreads();
  const int xsw = (lr & 7) << 4;
  for (int kt = 0; kt < 16; ++kt) {
    if (kt + 1 < 16) XW_STAGE((kt + 1) & 1, kt + 1);
    const char* Ab = (const char*)&Asb[kt & 1][0] + (wr * 64 + lr) * 128;
    const char* Bb = (const char*)&Bsb[kt & 1][0] + (wc * 64 + lr) * 128;
#pragma unroll
    for (int ks = 0; ks < 2; ++ks) {
      const int kb = (ks * 64 + ko * 16) ^ xsw;
      bf16x8 a[4], b[4];
#pragma unroll
      for (int mi = 0; mi < 4; ++mi) a[mi] = *(const bf16x8*)(Ab + mi * 2048 + kb);
#pragma unroll
      for (int ni = 0; ni < 4; ++ni) b[ni] = *(const bf16x8*)(Bb + ni * 2048 + kb);
#pragma unroll
      for (int mi = 0; mi < 4; ++mi)
#pragma unroll
        for (int ni = 0; ni < 4; ++ni)
          acc[mi][ni] = __builtin_amdgcn_mfma_f32_16x16x32_bf16(a[mi], b[ni], acc[mi][ni], 0, 0, 0);
    }
    __syncthreads();
  }

  const int rr = ko * 4;
#pragma unroll
  for (int ni = 0; ni < 4; ++ni) {
    const int n = n0 + wc * 64 + ni * 16 + lr;
    const int gg = n >> 10;
    const int jj = n & 1023;
    const float bn = bias[n];
#pragma unroll
    for (int mi = 0; mi < 4; ++mi) {
#pragma unroll
      for (int r = 0; r < 4; ++r) {
        const int m = m0 + wr * 64 + mi * 16 + rr + r;
        const int tt = m >> 7;
        const int btp = (m & 127) >> 5;
        const int r32 = m & 31;
        xwg[((((size_t)tt * 4 + btp) * 64 + (jj >> 4)) * 512 + r32 * 16 + (jj & 15)) * 4 + gg] =
            f2bf(acc[mi][ni][r] + bn);
      }
    }
  }
}

// ---------------------------------------------------------------------------
// Persistent LSTM recurrence. 256 blocks (1/CU) x 512 thr.
// Block (jt=bid&63, btp=bid>>6) touches ONLY h rows [btp*32,+32): 4
// independent groups of 64 blocks, per-group sync.
// h transport: per-step RING (each address written once via sc write-through,
// read once) -> readers use normal cached global_load_lds w=16 (pipelined,
// same-XCD same-group blocks share the tile through L2).
// Barrier (R10: DIRECT POLL — 2 L3 RTTs, not 4): after block-wide drain,
// tid 0 sc-stores generation t+1 to its own arrival word; wave 0 polls the
// group's 64 words with one 64-lane sc-load + __all. No aggregator, no flag.
// Wh resident forever: k-half in LDS (swizzled) + k-half in 16 VGPR frags.
// ---------------------------------------------------------------------------
__global__ __launch_bounds__(512) void lstm_persist5(
    const ushort_t* __restrict__ hbf0,  // [128][1024] premasked bf16
    const float* __restrict__ c0,       // [128][1024] raw
    const float* __restrict__ reset,    // [T][128]
    const ushort_t* __restrict__ xwg,   // relayout, bias included
    const ushort_t* __restrict__ WT,    // [4096][2048]
    float* __restrict__ out,            // [T*128][1024] then hT, cT
    ushort_t* __restrict__ hring,       // [T][128][1024] premasked bf16 ring
    uint_t* __restrict__ bar)           // [4][256] arrival words, zeroed
{
  __shared__ ushort_t WhL[64 * 512];   // [nr][k half], swizzled, 64 KB
  __shared__ ushort_t Ah[32 * 1024];   // [row][k], swizzled, 64 KB
  __shared__ float sc[2][4][16][17];   // [mh][g][brow][jcol], 8.7 KB

  const int tid = threadIdx.x;
  const int bid = blockIdx.x;   // 0..255
  const int jt = bid & 63;
  const int btp = bid >> 6;     // 0..3 = batch-group
  const int b0 = btp * 32;
  const int lane = tid & 63;
  const int wid = tid >> 6;     // 0..7
  const int g = wid & 3;
  const int mh = wid >> 2;
  const int lr = lane & 15;
  const int ko = lane >> 4;
  const size_t SE = (size_t)B_SZ * H_SZ;

  uint_t* const arr = bar + btp * 256;  // this group's 64 arrival words

  // ---- stage Wh k in [1024,1536) into LDS (once) ----
  for (int p = 0; p < 8; ++p) {
    const int id = p * 512 + tid;       // 0..4095
    const int wrw = id >> 6;            // 0..63 local n-row
    const int kb = (id & 63) * 16;      // byte in [0,1024)
    const int n = (wrw >> 4) * H_SZ + jt * 16 + (wrw & 15);
    const uint4 v = *(const uint4*)((const char*)WT + (size_t)n * 4096 + 2048 + kb);
    *(uint4*)((char*)WhL + wrw * 1024 + (kb ^ ((wrw & 7) << 4))) = v;
  }

  // ---- permanent B regs: Wh k in [1536,2048) ----
  const char* wrow = (const char*)WT + (size_t)(g * H_SZ + jt * 16 + lr) * 4096;
  bf16x8 breg[16];
#pragma unroll
  for (int q = 0; q < 16; ++q)
    breg[q] = *(const bf16x8*)(wrow + 3072 + q * 64 + ko * 16);

  // ---- per-thread output element state ----
  const int row = tid >> 4;     // 0..31
  const int col = tid & 15;
  const int b = b0 + row;
  const int j = jt * 16 + col;
  const size_t so = (size_t)b * H_SZ + j;
  float creg = c0[so] * (1.0f - reset[b]);

  const int swzl = (lr & 7) << 4;
  const char* aBase = (const char*)Ah + (mh * 16 + lr) * 2048;
  const char* bBase = (const char*)WhL + (g * 16 + lr) * 1024;

  // prefetched per-step operands (step 0 / mask for t=1)
  ull_t xwv = *(const ull_t*)(xwg + (((size_t)btp * 64 + jt) * 512 + tid) * 4);
  float mn = 1.0f - reset[B_SZ + b];

  for (int t = 0; t < T_STEPS; ++t) {
    // ---- A-stage: 32 h-rows via cached global_load_lds (pre-swizzled src) --
    const char* hsrc = (t == 0) ? (const char*)hbf0
                                : (const char*)(hring + (size_t)t * SE);
#pragma unroll
    for (int i = 0; i < 8; ++i) {
      const int c = wid * 8 + i;        // 0..63 (1KB chunks)
      const int hrow = c >> 1;          // 0..31
      const int half = (c & 1) * 1024;  // byte offset in 2048B row
      const int kb = half + lane * 16;
      const int src = kb ^ ((hrow & 7) << 4);
      GLOAD_LDS16(hsrc + (size_t)(b0 + hrow) * 2048 + src,
                  (char*)Ah + hrow * 2048 + half);
    }
    __syncthreads();

    // ---- GEMM: 16x16 out per wave, K=1024 (LDS half + reg half) ----
    f32x4 acc = {};
#pragma unroll
    for (int ks = 0; ks < 16; ++ks) {
      bf16x8 a = *(const bf16x8*)(aBase + ((ks * 64 + ko * 16) ^ swzl));
      bf16x8 bb = *(const bf16x8*)(bBase + ((ks * 64 + ko * 16) ^ swzl));
      acc = __builtin_amdgcn_mfma_f32_16x16x32_bf16(a, bb, acc, 0, 0, 0);
    }
#pragma unroll
    for (int ks = 0; ks < 16; ++ks) {
      bf16x8 a = *(const bf16x8*)(aBase + (((16 + ks) * 64 + ko * 16) ^ swzl));
      acc = __builtin_amdgcn_mfma_f32_16x16x32_bf16(a, breg[ks], acc, 0, 0, 0);
    }
#pragma unroll
    for (int r = 0; r < 4; ++r) sc[mh][g][ko * 4 + r][lr] = acc[r];
    __syncthreads();

    // ---- fused elementwise: 512 threads -> 32 rows x 16 cols ----
    const float gi = sc[row >> 4][0][row & 15][col] + bf2f((ushort_t)xwv);
    const float gg = sc[row >> 4][1][row & 15][col] + bf2f((ushort_t)(xwv >> 16));
    const float gf = sc[row >> 4][2][row & 15][col] + bf2f((ushort_t)(xwv >> 32));
    const float go = sc[row >> 4][3][row & 15][col] + bf2f((ushort_t)(xwv >> 48));
    const float f = sigf(gf + 1.0f);
    const float cn = f * creg + sigf(gi) * tanhfast(gg);
    const float hn = sigf(go) * tanhfast(cn);
    out[(size_t)t * SE + so] = hn;
    creg = cn * mn;

    if (t < T_STEPS - 1) {
      // h_{t+1} premasked -> hring[t+1] (write-through; fresh address)
      __hip_atomic_store(hring + (size_t)(t + 1) * SE + so, f2bf(hn * mn),
                         __ATOMIC_RELAXED, __HIP_MEMORY_SCOPE_AGENT);
      asm volatile("s_waitcnt vmcnt(0)" ::: "memory");  // drain h to L3
      __syncthreads();                                  // whole block drained

      // own-word arrival (monotonic generation; no contention)
      if (tid == 0)
        __hip_atomic_store(&arr[jt], (uint_t)(t + 1),
                           __ATOMIC_RELAXED, __HIP_MEMORY_SCOPE_AGENT);

      // prefetch next step's operands (independent of the barrier)
      xwv = *(const ull_t*)(xwg + ((((size_t)(t + 1) * 4 + btp) * 64 + jt) * 512 + tid) * 4);
      mn = (t + 1 < T_STEPS - 1) ? (1.0f - reset[(size_t)(t + 2) * B_SZ + b]) : 1.0f;

      // ---- direct poll: wave 0 watches all 64 group arrival words ----
      if (wid == 0) {
        uint_t it = 0;
        for (;;) {
          const uint_t v = __hip_atomic_load(&arr[lane], __ATOMIC_RELAXED,
                                             __HIP_MEMORY_SCOPE_AGENT);
          if (__all((int)v > t)) break;
          __builtin_amdgcn_s_sleep(1);
          if (++it > 1000000u) break;  // bounded: fail visibly, don't hang
        }
      }
      __syncthreads();
    } else {
      float* hT = out + (size_t)T_STEPS * SE;
      float* cT = hT + SE;
      hT[so] = hn;
      cT[so] = cn;  // unmasked at last step
    }
  }
}

extern "C" void kernel_launch(void* const* d_in, const int* in_sizes, int n_in,
                              void* d_out, int out_size, void* d_ws, size_t ws_size,
                              hipStream_t stream) {
  (void)in_sizes; (void)n_in; (void)out_size; (void)ws_size;
  const float* x = (const float*)d_in[0];
  const float* h0 = (const float*)d_in[1];
  const float* c0 = (const float*)d_in[2];
  const float* reset = (const float*)d_in[3];
  const float* W = (const float*)d_in[4];
  const float* bias = (const float*)d_in[5];
  float* out = (float*)d_out;

  const size_t TB = (size_t)T_STEPS * B_SZ;  // 16384
  const size_t SE = (size_t)B_SZ * H_SZ;     // 131072

  // ws layout (~218 MB total; proven ws_size >= 269 MB in R1)
  char* p = (char*)d_ws;
  uint_t* bar = (uint_t*)p;               p += 4096;
  ushort_t* WT = (ushort_t*)p;            p += (size_t)G4 * KW * 2;   // 16.8MB
  ushort_t* xbf = (ushort_t*)p;           p += TB * D_SZ * 2;         // 33.6MB
  ushort_t* xwg = (ushort_t*)p;           p += TB * G4 * 2;           // 134.2MB
  ushort_t* hbf0 = (ushort_t*)p;          p += SE * 2;                // 0.26MB
  ushort_t* hring = (ushort_t*)p;         p += (size_t)T_STEPS * SE * 2;  // 33.6MB

  hipMemsetAsync(bar, 0, 4096, stream);
  convert_x<<<dim3((int)(TB * D_SZ / 8 / 256)), 256, 0, stream>>>(x, xbf);
  transpose_w<<<dim3(KW / 32, G4 / 32), 256, 0, stream>>>(W, WT);
  init_state<<<dim3((int)((SE + 255) / 256)), 256, 0, stream>>>(h0, reset, hbf0);
  xw_mfma2<<<dim3(4096), 256, 0, stream>>>(xbf, WT, bias, xwg);

  lstm_persist5<<<dim3(256), 512, 0, stream>>>(hbf0, c0, reset, xwg, WT, out, hring, bar);
}

// Round 11
// 768.939 us; speedup vs baseline: 1.5318x; 1.1498x over previous
//
#include <hip/hip_runtime.h>
#include <math.h>

#define T_STEPS 128
#define B_SZ 128
#define D_SZ 1024
#define H_SZ 1024
#define G4 4096
#define KW 2048  // rows of W = D+H

typedef __attribute__((ext_vector_type(8))) short bf16x8;
typedef __attribute__((ext_vector_type(4))) float f32x4;
typedef unsigned short ushort_t;
typedef unsigned int uint_t;
typedef unsigned long long ull_t;

__device__ __forceinline__ float sigf(float x) { return 1.0f / (1.0f + __expf(-x)); }
__device__ __forceinline__ float tanhfast(float x) { return 1.0f - 2.0f * sigf(-2.0f * x); }

__device__ __forceinline__ ushort_t f2bf(float f) {
  uint_t u = __float_as_uint(f);
  return (ushort_t)((u + 0x7fffu + ((u >> 16) & 1u)) >> 16);
}
__device__ __forceinline__ float bf2f(ushort_t s) {
  return __uint_as_float(((uint_t)s) << 16);
}

#define GLOAD_LDS16(gp, lp)                                                  \
  __builtin_amdgcn_global_load_lds(                                          \
      (const __attribute__((address_space(1))) unsigned int*)(const void*)(gp), \
      (__attribute__((address_space(3))) unsigned int*)(void*)(lp), 16, 0, 0)

// ---------------------------------------------------------------------------
// x fp32 [16384][1024] -> bf16 same layout. 8 elems/thread.
// ---------------------------------------------------------------------------
__global__ __launch_bounds__(256) void convert_x(const float* __restrict__ x,
                                                 ushort_t* __restrict__ xbf) {
  const size_t i8 = ((size_t)blockIdx.x * 256 + threadIdx.x) * 8;
  if (i8 + 8 > (size_t)T_STEPS * B_SZ * D_SZ) return;
  float4 a = *(const float4*)&x[i8];
  float4 b = *(const float4*)&x[i8 + 4];
  ushort_t o[8] = {f2bf(a.x), f2bf(a.y), f2bf(a.z), f2bf(a.w),
                   f2bf(b.x), f2bf(b.y), f2bf(b.z), f2bf(b.w)};
  *(uint4*)&xbf[i8] = *(uint4*)o;
}

// ---------------------------------------------------------------------------
// W fp32 [2048][4096] -> WT bf16 [4096][2048]  (WT[n][k] = W[k][n])
// ---------------------------------------------------------------------------
__global__ __launch_bounds__(256) void transpose_w(const float* __restrict__ W,
                                                   ushort_t* __restrict__ WT) {
  __shared__ float t[32][33];
  const int tx = threadIdx.x & 31;
  const int ty = threadIdx.x >> 5;  // 0..7
  const int k0 = blockIdx.x * 32;
  const int n0 = blockIdx.y * 32;
#pragma unroll
  for (int i = 0; i < 4; ++i)
    t[ty + i * 8][tx] = W[(size_t)(k0 + ty + i * 8) * G4 + n0 + tx];
  __syncthreads();
#pragma unroll
  for (int i = 0; i < 4; ++i)
    WT[(size_t)(n0 + ty + i * 8) * KW + k0 + tx] = f2bf(t[tx][ty + i * 8]);
}

// ---------------------------------------------------------------------------
// hbf0 = bf16(h0 * (1-reset[0]))
// ---------------------------------------------------------------------------
__global__ __launch_bounds__(256) void init_state(const float* __restrict__ h0,
                                                  const float* __restrict__ reset0,
                                                  ushort_t* __restrict__ hbf0) {
  const int i = blockIdx.x * 256 + threadIdx.x;
  if (i >= B_SZ * H_SZ) return;
  hbf0[i] = f2bf(h0[i] * (1.0f - reset0[i >> 10]));
}

// ---------------------------------------------------------------------------
// Gate pre-activation from x:  val = bias[n] + sum_k xbf[m][k]*WT[n][k].
// xwg layout (v3, 8B-packable): elem idx =
//   (((t*4 + btp)*64 + jt)*2048) + g*512 + c*32 + r32
// where m = t*128 + btp*32 + r32, n = g*1024 + jt*16 + c.
// Supertile swizzle: XCD x = bid&7 owns nt in [4x,4x+4); within XCD, 32-block
// supertiles of 8 mt x 4 nt (3MB working set ~ L2-resident).
// ---------------------------------------------------------------------------
__global__ __launch_bounds__(256) void xw_mfma3(const ushort_t* __restrict__ xbf,
                                                const ushort_t* __restrict__ WT,
                                                const float* __restrict__ bias,
                                                ushort_t* __restrict__ xwg) {
  __shared__ ushort_t Asb[2][128 * 64];  // [buf][row*64+k], 16KB each
  __shared__ ushort_t Bsb[2][128 * 64];

  const int bid = blockIdx.x;            // 4096 blocks
  const int xcd = bid & 7;
  const int ib = bid >> 3;               // 0..511
  const int mt = (ib >> 5) * 8 + (ib & 7);        // 0..127
  const int nt = xcd * 4 + ((ib >> 3) & 3);       // 0..31
  const int m0 = mt * 128, n0 = nt * 128;
  const int tid = threadIdx.x, lane = tid & 63, wid = tid >> 6;
  const int wr = wid >> 1, wc = wid & 1;
  const int lr = lane & 15, ko = lane >> 4;
  const int srow = lane >> 3;            // 0..7 row within chunk
  const int skb = (lane & 7) * 16;       // byte within row-window

  f32x4 acc[4][4] = {};

#define XW_STAGE(buf, kt)                                                      \
  {                                                                            \
    const int k0b = (kt) * 128;                                                \
    _Pragma("unroll") for (int i = 0; i < 4; ++i) {                            \
      const int c = wid * 4 + i;                                               \
      const int row = c * 8 + srow;                                            \
      const int sw = skb ^ ((row & 7) << 4);                                   \
      GLOAD_LDS16((const char*)xbf + (size_t)(m0 + row) * 2048 + k0b + sw,     \
                  (char*)&Asb[buf][0] + c * 1024);                             \
      GLOAD_LDS16((const char*)WT + (size_t)(n0 + row) * 4096 + k0b + sw,      \
                  (char*)&Bsb[buf][0] + c * 1024);                             \
    }                                                                          \
  }

  XW_STAGE(0, 0);
  __syncthreads();
  const int xsw = (lr & 7) << 4;
  for (int kt = 0; kt < 16; ++kt) {
    if (kt + 1 < 16) XW_STAGE((kt + 1) & 1, kt + 1);
    const char* Ab = (const char*)&Asb[kt & 1][0] + (wr * 64 + lr) * 128;
    const char* Bb = (const char*)&Bsb[kt & 1][0] + (wc * 64 + lr) * 128;
#pragma unroll
    for (int ks = 0; ks < 2; ++ks) {
      const int kb = (ks * 64 + ko * 16) ^ xsw;
      bf16x8 a[4], b[4];
#pragma unroll
      for (int mi = 0; mi < 4; ++mi) a[mi] = *(const bf16x8*)(Ab + mi * 2048 + kb);
#pragma unroll
      for (int ni = 0; ni < 4; ++ni) b[ni] = *(const bf16x8*)(Bb + ni * 2048 + kb);
#pragma unroll
      for (int mi = 0; mi < 4; ++mi)
#pragma unroll
        for (int ni = 0; ni < 4; ++ni)
          acc[mi][ni] = __builtin_amdgcn_mfma_f32_16x16x32_bf16(a[mi], b[ni], acc[mi][ni], 0, 0, 0);
    }
    __syncthreads();
  }

  // epilogue: pack 4 r-values -> one 8B store each (16 stores/thread)
  const int rr = ko * 4;
#pragma unroll
  for (int ni = 0; ni < 4; ++ni) {
    const int n = n0 + wc * 64 + ni * 16 + lr;
    const int g = n >> 10;
    const int jtn = (n & 1023) >> 4;     // jt of this col
    const float bn = bias[n];
#pragma unroll
    for (int mi = 0; mi < 4; ++mi) {
      const int m = m0 + wr * 64 + mi * 16 + rr;
      const int tt = m >> 7;
      const int btp = (m & 127) >> 5;
      const int r32 = m & 31;            // = (mi&1)*16 + ko*4, 8B aligned
      ushort_t tmp[4];
#pragma unroll
      for (int r = 0; r < 4; ++r) tmp[r] = f2bf(acc[mi][ni][r] + bn);
      *(ull_t*)(xwg + (((size_t)tt * 4 + btp) * 64 + jtn) * 2048 + g * 512 + lr * 32 + r32) =
          *(ull_t*)tmp;
    }
  }
}

// ---------------------------------------------------------------------------
// Persistent LSTM recurrence v6. 256 blocks (1/CU) x 512 thr.
// vs v5: (a) 4 independent MFMA acc chains; (b) ALL waves poll arrivals and
// start their own A-chunk loads on detection (post-poll syncthreads removed;
// Ah reuse is protected by the post-drain syncthreads); (c) h stores packed
// 4->1 via __shfl_down into 8B sc-stores (drain ops 512->128).
// ---------------------------------------------------------------------------
__global__ __launch_bounds__(512) void lstm_persist6(
    const ushort_t* __restrict__ hbf0,  // [128][1024] premasked bf16
    const float* __restrict__ c0,       // [128][1024] raw
    const float* __restrict__ reset,    // [T][128]
    const ushort_t* __restrict__ xwg,   // v3 layout, bias included
    const ushort_t* __restrict__ WT,    // [4096][2048]
    float* __restrict__ out,            // [T*128][1024] then hT, cT
    ushort_t* __restrict__ hring,       // [T][128][1024] premasked bf16 ring
    uint_t* __restrict__ bar)           // [4][256] arrival words, zeroed
{
  __shared__ ushort_t WhL[64 * 512];   // [nr][k half], swizzled, 64 KB
  __shared__ ushort_t Ah[32 * 1024];   // [row][k], swizzled, 64 KB
  __shared__ float sc[2][4][16][17];   // [mh][g][brow][jcol], 8.7 KB

  const int tid = threadIdx.x;
  const int bid = blockIdx.x;   // 0..255
  const int jt = bid & 63;
  const int btp = bid >> 6;     // 0..3 = batch-group
  const int b0 = btp * 32;
  const int lane = tid & 63;
  const int wid = tid >> 6;     // 0..7
  const int g = wid & 3;
  const int mh = wid >> 2;
  const int lr = lane & 15;
  const int ko = lane >> 4;
  const size_t SE = (size_t)B_SZ * H_SZ;

  uint_t* const arr = bar + btp * 256;  // this group's 64 arrival words

  // ---- stage Wh k in [1024,1536) into LDS (once) ----
  for (int p = 0; p < 8; ++p) {
    const int id = p * 512 + tid;       // 0..4095
    const int wrw = id >> 6;            // 0..63 local n-row
    const int kb = (id & 63) * 16;      // byte in [0,1024)
    const int n = (wrw >> 4) * H_SZ + jt * 16 + (wrw & 15);
    const uint4 v = *(const uint4*)((const char*)WT + (size_t)n * 4096 + 2048 + kb);
    *(uint4*)((char*)WhL + wrw * 1024 + (kb ^ ((wrw & 7) << 4))) = v;
  }

  // ---- permanent B regs: Wh k in [1536,2048) ----
  const char* wrow = (const char*)WT + (size_t)(g * H_SZ + jt * 16 + lr) * 4096;
  bf16x8 breg[16];
#pragma unroll
  for (int q = 0; q < 16; ++q)
    breg[q] = *(const bf16x8*)(wrow + 3072 + q * 64 + ko * 16);

  // ---- per-thread output element state ----
  const int row = tid >> 4;     // 0..31
  const int col = tid & 15;
  const int b = b0 + row;
  const int j = jt * 16 + col;
  const size_t so = (size_t)b * H_SZ + j;
  float creg = c0[so] * (1.0f - reset[b]);

  const int swzl = (lr & 7) << 4;
  const char* aBase = (const char*)Ah + (mh * 16 + lr) * 2048;
  const char* bBase = (const char*)WhL + (g * 16 + lr) * 1024;

  // prefetched per-step operands (step 0 / mask for t=1)
  ushort_t xq0, xq1, xq2, xq3;
  {
    const ushort_t* xp = xwg + (((size_t)btp) * 64 + jt) * 2048 + col * 32 + row;
    xq0 = xp[0]; xq1 = xp[512]; xq2 = xp[1024]; xq3 = xp[1536];
  }
  float mn = 1.0f - reset[B_SZ + b];

  for (int t = 0; t < T_STEPS; ++t) {
    // ---- per-wave: poll own copy of arrivals, then start own A-chunks ----
    if (t > 0) {
      uint_t it = 0;
      for (;;) {
        const uint_t v = __hip_atomic_load(&arr[lane], __ATOMIC_RELAXED,
                                           __HIP_MEMORY_SCOPE_AGENT);
        if (__all((int)v >= t)) break;
        __builtin_amdgcn_s_sleep(1);
        if (++it > 1000000u) break;  // bounded: fail visibly, don't hang
      }
    }
    const char* hsrc = (t == 0) ? (const char*)hbf0
                                : (const char*)(hring + (size_t)t * SE);
#pragma unroll
    for (int i = 0; i < 8; ++i) {
      const int c = wid * 8 + i;        // 0..63 (1KB chunks)
      const int hrow = c >> 1;          // 0..31
      const int half = (c & 1) * 1024;  // byte offset in 2048B row
      const int kb = half + lane * 16;
      const int src = kb ^ ((hrow & 7) << 4);
      GLOAD_LDS16(hsrc + (size_t)(b0 + hrow) * 2048 + src,
                  (char*)Ah + hrow * 2048 + half);
    }
    __syncthreads();  // all A-chunks landed (implicit vmcnt drain)

    // ---- GEMM: 16x16 out per wave, K=1024; 4 independent acc chains ----
    f32x4 ac0 = {}, ac1 = {}, ac2 = {}, ac3 = {};
#pragma unroll
    for (int q = 0; q < 4; ++q) {
      bf16x8 a0 = *(const bf16x8*)(aBase + (((q * 4 + 0) * 64 + ko * 16) ^ swzl));
      bf16x8 b0f = *(const bf16x8*)(bBase + (((q * 4 + 0) * 64 + ko * 16) ^ swzl));
      ac0 = __builtin_amdgcn_mfma_f32_16x16x32_bf16(a0, b0f, ac0, 0, 0, 0);
      bf16x8 a1 = *(const bf16x8*)(aBase + (((q * 4 + 1) * 64 + ko * 16) ^ swzl));
      bf16x8 b1f = *(const bf16x8*)(bBase + (((q * 4 + 1) * 64 + ko * 16) ^ swzl));
      ac1 = __builtin_amdgcn_mfma_f32_16x16x32_bf16(a1, b1f, ac1, 0, 0, 0);
      bf16x8 a2 = *(const bf16x8*)(aBase + (((q * 4 + 2) * 64 + ko * 16) ^ swzl));
      bf16x8 b2f = *(const bf16x8*)(bBase + (((q * 4 + 2) * 64 + ko * 16) ^ swzl));
      ac2 = __builtin_amdgcn_mfma_f32_16x16x32_bf16(a2, b2f, ac2, 0, 0, 0);
      bf16x8 a3 = *(const bf16x8*)(aBase + (((q * 4 + 3) * 64 + ko * 16) ^ swzl));
      bf16x8 b3f = *(const bf16x8*)(bBase + (((q * 4 + 3) * 64 + ko * 16) ^ swzl));
      ac3 = __builtin_amdgcn_mfma_f32_16x16x32_bf16(a3, b3f, ac3, 0, 0, 0);
    }
#pragma unroll
    for (int q = 0; q < 4; ++q) {
      bf16x8 a0 = *(const bf16x8*)(aBase + (((16 + q * 4 + 0) * 64 + ko * 16) ^ swzl));
      ac0 = __builtin_amdgcn_mfma_f32_16x16x32_bf16(a0, breg[q * 4 + 0], ac0, 0, 0, 0);
      bf16x8 a1 = *(const bf16x8*)(aBase + (((16 + q * 4 + 1) * 64 + ko * 16) ^ swzl));
      ac1 = __builtin_amdgcn_mfma_f32_16x16x32_bf16(a1, breg[q * 4 + 1], ac1, 0, 0, 0);
      bf16x8 a2 = *(const bf16x8*)(aBase + (((16 + q * 4 + 2) * 64 + ko * 16) ^ swzl));
      ac2 = __builtin_amdgcn_mfma_f32_16x16x32_bf16(a2, breg[q * 4 + 2], ac2, 0, 0, 0);
      bf16x8 a3 = *(const bf16x8*)(aBase + (((16 + q * 4 + 3) * 64 + ko * 16) ^ swzl));
      ac3 = __builtin_amdgcn_mfma_f32_16x16x32_bf16(a3, breg[q * 4 + 3], ac3, 0, 0, 0);
    }
    const f32x4 acc = (ac0 + ac1) + (ac2 + ac3);
#pragma unroll
    for (int r = 0; r < 4; ++r) sc[mh][g][ko * 4 + r][lr] = acc[r];
    __syncthreads();

    // ---- fused elementwise: 512 threads -> 32 rows x 16 cols ----
    const float gi = sc[row >> 4][0][row & 15][col] + bf2f(xq0);
    const float gg = sc[row >> 4][1][row & 15][col] + bf2f(xq1);
    const float gf = sc[row >> 4][2][row & 15][col] + bf2f(xq2);
    const float go = sc[row >> 4][3][row & 15][col] + bf2f(xq3);
    const float f = sigf(gf + 1.0f);
    const float cn = f * creg + sigf(gi) * tanhfast(gg);
    const float hn = sigf(go) * tanhfast(cn);
    out[(size_t)t * SE + so] = hn;
    creg = cn * mn;

    if (t < T_STEPS - 1) {
      // pack 4 neighboring cols' h into one 8B sc-store (128 stores/block)
      const uint_t hm = (uint_t)f2bf(hn * mn);
      const uint_t h1 = (uint_t)__shfl_down((int)hm, 1);
      const uint_t h2 = (uint_t)__shfl_down((int)hm, 2);
      const uint_t h3 = (uint_t)__shfl_down((int)hm, 3);
      if ((col & 3) == 0) {
        const ull_t pk = (ull_t)(hm & 0xffffu) | ((ull_t)(h1 & 0xffffu) << 16) |
                         ((ull_t)(h2 & 0xffffu) << 32) | ((ull_t)(h3 & 0xffffu) << 48);
        __hip_atomic_store((ull_t*)(hring + (size_t)(t + 1) * SE + so), pk,
                           __ATOMIC_RELAXED, __HIP_MEMORY_SCOPE_AGENT);
      }
      asm volatile("s_waitcnt vmcnt(0)" ::: "memory");  // drain h to L3
      __syncthreads();                                  // whole block drained

      // own-word arrival (monotonic generation; no contention)
      if (tid == 0)
        __hip_atomic_store(&arr[jt], (uint_t)(t + 1),
                           __ATOMIC_RELAXED, __HIP_MEMORY_SCOPE_AGENT);

      // prefetch next step's operands (hidden under next poll)
      const ushort_t* xp = xwg + (((size_t)(t + 1) * 4 + btp) * 64 + jt) * 2048 + col * 32 + row;
      xq0 = xp[0]; xq1 = xp[512]; xq2 = xp[1024]; xq3 = xp[1536];
      mn = (t + 1 < T_STEPS - 1) ? (1.0f - reset[(size_t)(t + 2) * B_SZ + b]) : 1.0f;
    } else {
      float* hT = out + (size_t)T_STEPS * SE;
      float* cT = hT + SE;
      hT[so] = hn;
      cT[so] = cn;  // unmasked at last step
    }
  }
}

extern "C" void kernel_launch(void* const* d_in, const int* in_sizes, int n_in,
                              void* d_out, int out_size, void* d_ws, size_t ws_size,
                              hipStream_t stream) {
  (void)in_sizes; (void)n_in; (void)out_size; (void)ws_size;
  const float* x = (const float*)d_in[0];
  const float* h0 = (const float*)d_in[1];
  const float* c0 = (const float*)d_in[2];
  const float* reset = (const float*)d_in[3];
  const float* W = (const float*)d_in[4];
  const float* bias = (const float*)d_in[5];
  float* out = (float*)d_out;

  const size_t TB = (size_t)T_STEPS * B_SZ;  // 16384
  const size_t SE = (size_t)B_SZ * H_SZ;     // 131072

  // ws layout (~218 MB total; proven ws_size >= 269 MB in R1)
  char* p = (char*)d_ws;
  uint_t* bar = (uint_t*)p;               p += 4096;
  ushort_t* WT = (ushort_t*)p;            p += (size_t)G4 * KW * 2;   // 16.8MB
  ushort_t* xbf = (ushort_t*)p;           p += TB * D_SZ * 2;         // 33.6MB
  ushort_t* xwg = (ushort_t*)p;           p += TB * G4 * 2;           // 134.2MB
  ushort_t* hbf0 = (ushort_t*)p;          p += SE * 2;                // 0.26MB
  ushort_t* hring = (ushort_t*)p;         p += (size_t)T_STEPS * SE * 2;  // 33.6MB

  hipMemsetAsync(bar, 0, 4096, stream);
  convert_x<<<dim3((int)(TB * D_SZ / 8 / 256)), 256, 0, stream>>>(x, xbf);
  transpose_w<<<dim3(KW / 32, G4 / 32), 256, 0, stream>>>(W, WT);
  init_state<<<dim3((int)((SE + 255) / 256)), 256, 0, stream>>>(h0, reset, hbf0);
  xw_mfma3<<<dim3(4096), 256, 0, stream>>>(xbf, WT, bias, xwg);

  lstm_persist6<<<dim3(256), 512, 0, stream>>>(hbf0, c0, reset, xwg, WT, out, hring, bar);
}